// Round 1
// baseline (171.821 us; speedup 1.0000x reference)
//
#include <hip/hip_runtime.h>
#include <math.h>

#define B_SAMPLES 4096
#define D_DIM 512
#define NCLS 100
#define NROWS 8192           // V * B
#define CPT 10               // classes per thread in kernel 1
#define INV_T (1.0f / 0.07f)

// ws layout (floats):
//   S     : [NCLS][NROWS]              offset 0
//   stats : M1[100] M2[100] E1[100] E2[100] P[100] N[100]   offset NCLS*NROWS
//   I1    : int[100]                   after stats

__global__ __launch_bounds__(256) void k_scores(const float* __restrict__ feats,
                                                const float* __restrict__ protos,
                                                float* __restrict__ S) {
    const int j = blockIdx.x * 256 + threadIdx.x;   // contrast row 0..8191
    const int cbase = blockIdx.y * CPT;
    const int v = j >> 12;                           // j / 4096
    const int b = j & (B_SAMPLES - 1);               // j % 4096
    // contrast[j][d] = feats[b][v][d], feats is [B][V][D] row-major
    const float4* __restrict__ row = (const float4*)(feats + (size_t)(b * 2 + v) * D_DIM);

    float acc[CPT];
#pragma unroll
    for (int c = 0; c < CPT; ++c) acc[c] = 0.f;

#pragma unroll 4
    for (int k = 0; k < D_DIM / 4; ++k) {
        const float4 f = row[k];
#pragma unroll
        for (int c = 0; c < CPT; ++c) {
            // uniform address across the wave -> scalar loads
            const float4 p = ((const float4*)(protos + (size_t)(cbase + c) * D_DIM))[k];
            acc[c] += f.x * p.x + f.y * p.y + f.z * p.z + f.w * p.w;
        }
    }
#pragma unroll
    for (int c = 0; c < CPT; ++c)
        S[(size_t)(cbase + c) * NROWS + j] = acc[c] * INV_T;
}

__global__ __launch_bounds__(256) void k_stats(const float* __restrict__ S,
                                               const int* __restrict__ labels,
                                               float* __restrict__ stats,
                                               int* __restrict__ I1) {
    const int c = blockIdx.x;
    const int tid = threadIdx.x;
    const float* __restrict__ row = S + (size_t)c * NROWS;

    __shared__ float red[256];
    __shared__ int redi[256];
    __shared__ float4 red4[256];

    // ---- pass 1: M1 (max) + argmax i1 ----
    float m = -INFINITY; int mi = 0;
    for (int j = tid; j < NROWS; j += 256) {
        const float x = row[j];
        if (x > m) { m = x; mi = j; }
    }
    red[tid] = m; redi[tid] = mi;
    __syncthreads();
    for (int s = 128; s > 0; s >>= 1) {
        if (tid < s && red[tid + s] > red[tid]) { red[tid] = red[tid + s]; redi[tid] = redi[tid + s]; }
        __syncthreads();
    }
    const float M1 = red[0];
    const int   i1 = redi[0];
    __syncthreads();

    // ---- pass 2: M2 = max excluding i1 ----
    m = -INFINITY;
    for (int j = tid; j < NROWS; j += 256) {
        if (j == i1) continue;
        m = fmaxf(m, row[j]);
    }
    red[tid] = m;
    __syncthreads();
    for (int s = 128; s > 0; s >>= 1) {
        if (tid < s) red[tid] = fmaxf(red[tid], red[tid + s]);
        __syncthreads();
    }
    const float M2 = red[0];
    __syncthreads();

    // ---- pass 3: E1 = sum exp(s-M1); E2 = sum_{j!=i1} exp(s-M2); P, n ----
    float e1 = 0.f, e2 = 0.f, p = 0.f, n = 0.f;
    for (int j = tid; j < NROWS; j += 256) {
        const float x = row[j];
        e1 += __expf(x - M1);
        if (j != i1) e2 += __expf(x - M2);
        if (labels[j & (B_SAMPLES - 1)] == c) { p += x - M1; n += 1.f; }
    }
    red4[tid] = make_float4(e1, e2, p, n);
    __syncthreads();
    for (int s = 128; s > 0; s >>= 1) {
        if (tid < s) {
            float4 a = red4[tid], b4 = red4[tid + s];
            red4[tid] = make_float4(a.x + b4.x, a.y + b4.y, a.z + b4.z, a.w + b4.w);
        }
        __syncthreads();
    }
    if (tid == 0) {
        float4 r = red4[0];
        stats[0 * NCLS + c] = M1;
        stats[1 * NCLS + c] = M2;
        stats[2 * NCLS + c] = r.x;   // E1
        stats[3 * NCLS + c] = r.y;   // E2
        stats[4 * NCLS + c] = r.z;   // P
        stats[5 * NCLS + c] = r.w;   // n
        I1[c] = i1;
    }
}

__global__ __launch_bounds__(1024) void k_loss(const float* __restrict__ S,
                                               const int* __restrict__ labels,
                                               const float* __restrict__ stats,
                                               const int* __restrict__ I1,
                                               float* __restrict__ out) {
    const int tid = threadIdx.x;
    float sum = 0.f;
    for (int i = tid; i < NROWS; i += 1024) {
        const int c = labels[i & (B_SAMPLES - 1)];
        const float M1 = stats[0 * NCLS + c];
        const float M2 = stats[1 * NCLS + c];
        const float E1 = stats[2 * NCLS + c];
        const float E2 = stats[3 * NCLS + c];
        const float P  = stats[4 * NCLS + c];
        const float N  = stats[5 * NCLS + c];
        const int   i1 = I1[c];

        const float s  = S[(size_t)c * NROWS + i];
        const float sm = s - M1;
        float logden;
        if (i == i1) {
            logden = (M2 - M1) + __logf(E2);     // rescaled, cancellation-free
        } else {
            logden = __logf(E1 - __expf(sm));    // E1 - exp(sm) >= 1 always here
        }
        const float nm1 = N - 1.0f;
        const float mlpp = (P - sm - nm1 * logden) / nm1;
        sum += -mlpp;
    }
    __shared__ float red[1024];
    red[tid] = sum;
    __syncthreads();
    for (int s = 512; s > 0; s >>= 1) {
        if (tid < s) red[tid] += red[tid + s];
        __syncthreads();
    }
    if (tid == 0) out[0] = red[0] / (float)NROWS;
}

extern "C" void kernel_launch(void* const* d_in, const int* in_sizes, int n_in,
                              void* d_out, int out_size, void* d_ws, size_t ws_size,
                              hipStream_t stream) {
    const float* feats  = (const float*)d_in[0];
    const int*   labels = (const int*)d_in[1];
    const float* protos = (const float*)d_in[2];
    float* out = (float*)d_out;

    float* S     = (float*)d_ws;
    float* stats = S + (size_t)NCLS * NROWS;
    int*   I1    = (int*)(stats + 6 * NCLS);

    dim3 g1(NROWS / 256, NCLS / CPT);
    k_scores<<<g1, 256, 0, stream>>>(feats, protos, S);
    k_stats<<<NCLS, 256, 0, stream>>>(S, labels, stats, I1);
    k_loss<<<1, 1024, 0, stream>>>(S, labels, stats, I1, out);
}

// Round 2
// 134.882 us; speedup vs baseline: 1.2739x; 1.2739x over previous
//
#include <hip/hip_runtime.h>
#include <math.h>

#define B_SAMPLES 4096
#define D_DIM 512
#define NCLS 100
#define NROWS 8192           // V * B
#define CPT 4                // classes per thread in k_scores
#define INV_T (1.0f / 0.07f)
#define STAT_THREADS 512
#define CAP 2048             // matched-row stash capacity (E[matches]=82)

// ws layout (floats): S : [NCLS][NROWS]

__global__ __launch_bounds__(256) void k_scores(const float* __restrict__ feats,
                                                const float* __restrict__ protos,
                                                float* __restrict__ S,
                                                float* __restrict__ out) {
    // zero the accumulator output (runs before k_stats_loss on the same stream)
    if (blockIdx.x == 0 && blockIdx.y == 0 && threadIdx.x == 0) out[0] = 0.f;

    const int j = blockIdx.x * 256 + threadIdx.x;   // contrast row 0..8191
    const int cbase = blockIdx.y * CPT;
    const int v = j >> 12;
    const int b = j & (B_SAMPLES - 1);
    // contrast[j][d] = feats[b][v][d]
    const float4* __restrict__ row = (const float4*)(feats + (size_t)(b * 2 + v) * D_DIM);
    const float4* __restrict__ p0  = (const float4*)(protos + (size_t)cbase * D_DIM);

    float acc[CPT] = {};
#pragma unroll 4
    for (int k = 0; k < D_DIM / 4; ++k) {
        const float4 f = row[k];
#pragma unroll
        for (int c = 0; c < CPT; ++c) {
            const float4 p = p0[c * (D_DIM / 4) + k];   // wave-uniform -> s_load
            acc[c] += f.x * p.x + f.y * p.y + f.z * p.z + f.w * p.w;
        }
    }
#pragma unroll
    for (int c = 0; c < CPT; ++c)
        S[(size_t)(cbase + c) * NROWS + j] = acc[c] * INV_T;
}

__global__ __launch_bounds__(STAT_THREADS) void k_stats_loss(const float* __restrict__ S,
                                                             const int* __restrict__ labels,
                                                             float* __restrict__ out) {
    const int c = blockIdx.x;
    const int tid = threadIdx.x;
    const float* __restrict__ row = S + (size_t)c * NROWS;

    __shared__ float sm1[STAT_THREADS];
    __shared__ float sm2[STAT_THREADS];
    __shared__ int   si1[STAT_THREADS];
    __shared__ float4 red4[STAT_THREADS];
    __shared__ float xs[CAP];
    __shared__ int   cnt;

    // ---- pass 1: top-2 (M1, argmax i1, M2) in ONE scan ----
    float m1 = -INFINITY, m2 = -INFINITY; int i1 = -1;
    for (int j = tid; j < NROWS; j += STAT_THREADS) {
        const float x = row[j];
        if (x > m1)      { m2 = m1; m1 = x; i1 = j; }
        else if (x > m2) { m2 = x; }
    }
    sm1[tid] = m1; sm2[tid] = m2; si1[tid] = i1;
    __syncthreads();
    for (int s = STAT_THREADS / 2; s > 0; s >>= 1) {
        if (tid < s) {
            const float bm1 = sm1[tid + s], bm2 = sm2[tid + s];
            if (bm1 > sm1[tid]) { sm2[tid] = fmaxf(sm1[tid], bm2); sm1[tid] = bm1; si1[tid] = si1[tid + s]; }
            else                { sm2[tid] = fmaxf(sm2[tid], bm1); }
        }
        __syncthreads();
    }
    const float M1 = sm1[0], M2 = sm2[0];
    const int   gi1 = si1[0];
    if (tid == 0) cnt = 0;
    __syncthreads();

    // ---- pass 2: E1, E2, P, stash matched sm values ----
    float e1 = 0.f, e2 = 0.f, p = 0.f;
    for (int j = tid; j < NROWS; j += STAT_THREADS) {
        const float x = row[j];
        const float sm = x - M1;
        e1 += __expf(sm);
        if (j != gi1) e2 += __expf(x - M2);
        if (labels[j & (B_SAMPLES - 1)] == c) {
            p += sm;
            if (j != gi1) { const int k = atomicAdd(&cnt, 1); if (k < CAP) xs[k] = sm; }
        }
    }
    red4[tid] = make_float4(e1, e2, p, 0.f);
    __syncthreads();   // also makes all xs[] appends + cnt visible
    for (int s = STAT_THREADS / 2; s > 0; s >>= 1) {
        if (tid < s) {
            const float4 a = red4[tid], b4 = red4[tid + s];
            red4[tid] = make_float4(a.x + b4.x, a.y + b4.y, a.z + b4.z, 0.f);
        }
        __syncthreads();
    }
    const float E1 = red4[0].x, E2 = red4[0].y, P = red4[0].z;
    const int total = cnt;
    __syncthreads();

    // ---- pass 3: sum of log(denom) over matched rows (tiny; LDS-resident) ----
    float ls = 0.f;
    if (total <= CAP) {
        for (int k = tid; k < total; k += STAT_THREADS)
            ls += __logf(E1 - __expf(xs[k]));          // >= 1 always (i1 term stays)
    } else {  // pathological fallback: rescan the row
        for (int j = tid; j < NROWS; j += STAT_THREADS)
            if (j != gi1 && labels[j & (B_SAMPLES - 1)] == c)
                ls += __logf(E1 - __expf(row[j] - M1));
    }
    red4[tid].x = ls;
    __syncthreads();
    for (int s = STAT_THREADS / 2; s > 0; s >>= 1) {
        if (tid < s) red4[tid].x += red4[tid + s].x;
        __syncthreads();
    }
    if (tid == 0) {
        float sumlog = red4[0].x;
        if (labels[gi1 & (B_SAMPLES - 1)] == c)
            sumlog += (M2 - M1) + __logf(E2);          // cancellation-free i==i1 term
        // sum_i(-mlpp_i) over class-c rows = sumlog - P ; mean over NROWS
        atomicAdd(out, (sumlog - P) / (float)NROWS);
    }
}

extern "C" void kernel_launch(void* const* d_in, const int* in_sizes, int n_in,
                              void* d_out, int out_size, void* d_ws, size_t ws_size,
                              hipStream_t stream) {
    const float* feats  = (const float*)d_in[0];
    const int*   labels = (const int*)d_in[1];
    const float* protos = (const float*)d_in[2];
    float* out = (float*)d_out;
    float* S = (float*)d_ws;

    dim3 g1(NROWS / 256, NCLS / CPT);                 // (32, 25)
    k_scores<<<g1, 256, 0, stream>>>(feats, protos, S, out);
    k_stats_loss<<<NCLS, STAT_THREADS, 0, stream>>>(S, labels, out);
}

// Round 3
// 111.745 us; speedup vs baseline: 1.5376x; 1.2071x over previous
//
#include <hip/hip_runtime.h>
#include <hip/hip_bf16.h>
#include <math.h>

#define B_SAMPLES 4096
#define DDIM 512
#define NCLS 100
#define NROWS 8192           // V * B
#define MPAD 112             // 7 * 16
#define INV_T (1.0f / 0.07f)
#define JB 8                 // j-chunks per class for stats kernels
#define CHUNK 1024           // NROWS / JB
#define STASH_CAP 256        // E[matches/class] = 82

typedef __attribute__((ext_vector_type(8))) short short8;      // 8 bf16
typedef __attribute__((ext_vector_type(8))) unsigned short ushort8;
typedef __attribute__((ext_vector_type(4))) float f32x4;

__device__ __forceinline__ unsigned short f2bf(float x) {
    __hip_bfloat16 h = __float2bfloat16(x);
    return *reinterpret_cast<unsigned short*>(&h);
}

// ---------------- kernel 1: convert fp32 -> bf16 (view-major reorder) + zero accums ----------------
__global__ __launch_bounds__(256) void k_convert(const float* __restrict__ feats,
                                                 const float* __restrict__ protos,
                                                 unsigned short* __restrict__ cB,
                                                 unsigned short* __restrict__ pB,
                                                 float* __restrict__ gE1, float* __restrict__ gE2,
                                                 float* __restrict__ gP, int* __restrict__ scnt,
                                                 float* __restrict__ out) {
    const int bid = blockIdx.x, tid = threadIdx.x;
    if (bid < 2048) {                       // contrast: 8192 x 512, 8 elems/thread
        const int t  = bid * 256 + tid;
        const int j  = t >> 6;              // contrast row (v-major)
        const int kk = (t & 63) << 3;
        const int v = j >> 12, b = j & (B_SAMPLES - 1);
        const float4* src = (const float4*)(feats + (size_t)(b * 2 + v) * DDIM + kk);
        const float4 f0 = src[0], f1 = src[1];
        ushort8 o;
        o[0] = f2bf(f0.x); o[1] = f2bf(f0.y); o[2] = f2bf(f0.z); o[3] = f2bf(f0.w);
        o[4] = f2bf(f1.x); o[5] = f2bf(f1.y); o[6] = f2bf(f1.z); o[7] = f2bf(f1.w);
        *reinterpret_cast<ushort8*>(cB + (size_t)j * DDIM + kk) = o;
    } else if (bid < 2076) {                // protos: 112 x 512 (zero-pad rows >= 100)
        const int t  = (bid - 2048) * 256 + tid;
        const int r  = t >> 6;
        const int kk = (t & 63) << 3;
        float4 f0 = {0,0,0,0}, f1 = {0,0,0,0};
        if (r < NCLS) {
            const float4* src = (const float4*)(protos + (size_t)r * DDIM + kk);
            f0 = src[0]; f1 = src[1];
        }
        ushort8 o;
        o[0] = f2bf(f0.x); o[1] = f2bf(f0.y); o[2] = f2bf(f0.z); o[3] = f2bf(f0.w);
        o[4] = f2bf(f1.x); o[5] = f2bf(f1.y); o[6] = f2bf(f1.z); o[7] = f2bf(f1.w);
        *reinterpret_cast<ushort8*>(pB + (size_t)r * DDIM + kk) = o;
    } else {                                // zero the atomics targets (ws is poisoned 0xAA)
        if (tid < NCLS) { gE1[tid] = 0.f; gE2[tid] = 0.f; gP[tid] = 0.f; scnt[tid] = 0; }
        if (tid == 255) out[0] = 0.f;
    }
}

// ---------------- kernel 2: S = protos_bf16 @ contrast_bf16^T / T via MFMA ----------------
// wave tile: 16 (M) x 32 (N); 7 M-tiles x 256 N-tiles = 1792 waves
__global__ __launch_bounds__(256) void k_gemm(const unsigned short* __restrict__ cB,
                                              const unsigned short* __restrict__ pB,
                                              float* __restrict__ S) {
    const int tile = blockIdx.x * 4 + (threadIdx.x >> 6);
    const int mt = tile % 7;
    const int nt = tile / 7;
    const int lane = threadIdx.x & 63;
    const int m  = lane & 15;
    const int kb = lane >> 4;               // 0..3
    // A frag: lane holds A[m][kb*8 + i] ; B frag: lane holds B[kb*8 + i][m] = contrast[n][k]
    const short* Ab = (const short*)pB + (size_t)(mt * 16 + m) * DDIM + kb * 8;
    const short* Bb = (const short*)cB + (size_t)(nt * 32 + m) * DDIM + kb * 8;
    f32x4 acc0 = {}, acc1 = {};
#pragma unroll
    for (int k = 0; k < 16; ++k) {          // K = 512 = 16 steps of 32
        const short8 a  = *reinterpret_cast<const short8*>(Ab + k * 32);
        const short8 b0 = *reinterpret_cast<const short8*>(Bb + k * 32);
        const short8 b1 = *reinterpret_cast<const short8*>(Bb + 16 * DDIM + k * 32);
        acc0 = __builtin_amdgcn_mfma_f32_16x16x32_bf16(a, b0, acc0, 0, 0, 0);
        acc1 = __builtin_amdgcn_mfma_f32_16x16x32_bf16(a, b1, acc1, 0, 0, 0);
    }
    // C/D: col = lane&15, row = (lane>>4)*4 + r   [measured m89/m91]
    const int row0 = mt * 16 + kb * 4;
    const int col  = nt * 32 + m;
#pragma unroll
    for (int r = 0; r < 4; ++r) {
        const int row = row0 + r;
        if (row < NCLS) {
            S[(size_t)row * NROWS + col]      = acc0[r] * INV_T;
            S[(size_t)row * NROWS + col + 16] = acc1[r] * INV_T;
        }
    }
}

// ---------------- kernel 3: per-(class, chunk) partial top-2 + argmax ----------------
__global__ __launch_bounds__(256) void k_top2(const float* __restrict__ S,
                                              float* __restrict__ pM1, float* __restrict__ pM2,
                                              int* __restrict__ pI1) {
    const int c = blockIdx.y, jb = blockIdx.x, tid = threadIdx.x;
    const float* row = S + (size_t)c * NROWS + jb * CHUNK;
    float m1 = -INFINITY, m2 = -INFINITY; int i1 = -1;
    for (int t = tid; t < CHUNK; t += 256) {
        const float x = row[t];
        if (x > m1)      { m2 = m1; m1 = x; i1 = jb * CHUNK + t; }
        else if (x > m2) { m2 = x; }
    }
    __shared__ float s1[256], s2[256];
    __shared__ int   si[256];
    s1[tid] = m1; s2[tid] = m2; si[tid] = i1;
    __syncthreads();
    for (int s = 128; s > 0; s >>= 1) {
        if (tid < s) {
            const float b1 = s1[tid + s], b2 = s2[tid + s];
            if (b1 > s1[tid]) { s2[tid] = fmaxf(s1[tid], b2); s1[tid] = b1; si[tid] = si[tid + s]; }
            else              { s2[tid] = fmaxf(s2[tid], b1); }
        }
        __syncthreads();
    }
    if (tid == 0) { pM1[c * JB + jb] = s1[0]; pM2[c * JB + jb] = s2[0]; pI1[c * JB + jb] = si[0]; }
}

// ---------------- kernel 4: per-(class, chunk) exp sums + stash matched values ----------------
__global__ __launch_bounds__(256) void k_expsum(const float* __restrict__ S,
                                                const int* __restrict__ labels,
                                                const float* __restrict__ pM1, const float* __restrict__ pM2,
                                                const int* __restrict__ pI1,
                                                float* __restrict__ gE1, float* __restrict__ gE2,
                                                float* __restrict__ gP,
                                                float* __restrict__ stash, int* __restrict__ scnt) {
    const int c = blockIdx.y, jb = blockIdx.x, tid = threadIdx.x;
    __shared__ float sM1, sM2; __shared__ int sI1;
    if (tid == 0) {   // deterministic merge of the 8 partials (same result in every block)
        float m1 = -INFINITY, m2 = -INFINITY; int i1 = -1;
        for (int p = 0; p < JB; ++p) {
            const float b1 = pM1[c * JB + p], b2 = pM2[c * JB + p];
            if (b1 > m1) { m2 = fmaxf(m1, b2); m1 = b1; i1 = pI1[c * JB + p]; }
            else         { m2 = fmaxf(m2, b1); }
        }
        sM1 = m1; sM2 = m2; sI1 = i1;
    }
    __syncthreads();
    const float M1 = sM1, M2 = sM2; const int i1 = sI1;
    const float* row = S + (size_t)c * NROWS;
    float e1 = 0.f, e2 = 0.f, p = 0.f;
    for (int t = tid; t < CHUNK; t += 256) {
        const int j = jb * CHUNK + t;
        const float x = row[j];
        const float sm = x - M1;
        e1 += __expf(sm);
        if (j != i1) e2 += __expf(x - M2);
        if (labels[j & (B_SAMPLES - 1)] == c) {
            p += sm;
            if (j != i1) {
                const int k = atomicAdd(&scnt[c], 1);
                if (k < STASH_CAP) stash[c * STASH_CAP + k] = sm;
            }
        }
    }
    __shared__ float r1[256], r2[256], r3[256];
    r1[tid] = e1; r2[tid] = e2; r3[tid] = p;
    __syncthreads();
    for (int s = 128; s > 0; s >>= 1) {
        if (tid < s) { r1[tid] += r1[tid + s]; r2[tid] += r2[tid + s]; r3[tid] += r3[tid + s]; }
        __syncthreads();
    }
    if (tid == 0) { atomicAdd(&gE1[c], r1[0]); atomicAdd(&gE2[c], r2[0]); atomicAdd(&gP[c], r3[0]); }
}

// ---------------- kernel 5: per-class finish (~82 logs) + accumulate loss ----------------
__global__ __launch_bounds__(64) void k_final(const float* __restrict__ S,
                                              const int* __restrict__ labels,
                                              const float* __restrict__ pM1, const float* __restrict__ pM2,
                                              const int* __restrict__ pI1,
                                              const float* __restrict__ gE1, const float* __restrict__ gE2,
                                              const float* __restrict__ gP,
                                              const float* __restrict__ stash, const int* __restrict__ scnt,
                                              float* __restrict__ out) {
    const int c = blockIdx.x, lane = threadIdx.x;
    float m1 = -INFINITY, m2 = -INFINITY; int i1 = -1;     // all lanes redundantly (uniform)
    for (int p = 0; p < JB; ++p) {
        const float b1 = pM1[c * JB + p], b2 = pM2[c * JB + p];
        if (b1 > m1) { m2 = fmaxf(m1, b2); m1 = b1; i1 = pI1[c * JB + p]; }
        else         { m2 = fmaxf(m2, b1); }
    }
    const float E1 = gE1[c], E2 = gE2[c], P = gP[c];
    const int total = scnt[c];
    float ls = 0.f;
    if (total <= STASH_CAP) {
        for (int k = lane; k < total; k += 64)
            ls += __logf(E1 - __expf(stash[c * STASH_CAP + k]));   // >= 1: i1 term remains
    } else {   // pathological fallback
        for (int j = lane; j < NROWS; j += 64)
            if (j != i1 && labels[j & (B_SAMPLES - 1)] == c)
                ls += __logf(E1 - __expf(S[(size_t)c * NROWS + j] - m1));
    }
    for (int o = 32; o > 0; o >>= 1) ls += __shfl_down(ls, o);
    if (lane == 0) {
        if (labels[i1 & (B_SAMPLES - 1)] == c)
            ls += (m2 - m1) + __logf(E2);                          // cancellation-free i==i1 term
        atomicAdd(out, (ls - P) / (float)NROWS);
    }
}

// ================= fallback path (proven r2 kernels, used if ws too small) =================
#define CPT 4
#define STAT_THREADS 512
#define FCAP 2048

__global__ __launch_bounds__(256) void k_scores_fb(const float* __restrict__ feats,
                                                   const float* __restrict__ protos,
                                                   float* __restrict__ S, float* __restrict__ out) {
    if (blockIdx.x == 0 && blockIdx.y == 0 && threadIdx.x == 0) out[0] = 0.f;
    const int j = blockIdx.x * 256 + threadIdx.x;
    const int cbase = blockIdx.y * CPT;
    const int v = j >> 12, b = j & (B_SAMPLES - 1);
    const float4* row = (const float4*)(feats + (size_t)(b * 2 + v) * DDIM);
    const float4* p0  = (const float4*)(protos + (size_t)cbase * DDIM);
    float acc[CPT] = {};
#pragma unroll 4
    for (int k = 0; k < DDIM / 4; ++k) {
        const float4 f = row[k];
#pragma unroll
        for (int c = 0; c < CPT; ++c) {
            const float4 p = p0[c * (DDIM / 4) + k];
            acc[c] += f.x * p.x + f.y * p.y + f.z * p.z + f.w * p.w;
        }
    }
#pragma unroll
    for (int c = 0; c < CPT; ++c) S[(size_t)(cbase + c) * NROWS + j] = acc[c] * INV_T;
}

__global__ __launch_bounds__(STAT_THREADS) void k_stats_loss_fb(const float* __restrict__ S,
                                                                const int* __restrict__ labels,
                                                                float* __restrict__ out) {
    const int c = blockIdx.x, tid = threadIdx.x;
    const float* row = S + (size_t)c * NROWS;
    __shared__ float sm1[STAT_THREADS], sm2[STAT_THREADS];
    __shared__ int si1[STAT_THREADS];
    __shared__ float4 red4[STAT_THREADS];
    __shared__ float xs[FCAP];
    __shared__ int cnt;
    float m1 = -INFINITY, m2 = -INFINITY; int i1 = -1;
    for (int j = tid; j < NROWS; j += STAT_THREADS) {
        const float x = row[j];
        if (x > m1) { m2 = m1; m1 = x; i1 = j; } else if (x > m2) m2 = x;
    }
    sm1[tid] = m1; sm2[tid] = m2; si1[tid] = i1;
    __syncthreads();
    for (int s = STAT_THREADS / 2; s > 0; s >>= 1) {
        if (tid < s) {
            const float b1 = sm1[tid + s], b2 = sm2[tid + s];
            if (b1 > sm1[tid]) { sm2[tid] = fmaxf(sm1[tid], b2); sm1[tid] = b1; si1[tid] = si1[tid + s]; }
            else               { sm2[tid] = fmaxf(sm2[tid], b1); }
        }
        __syncthreads();
    }
    const float M1 = sm1[0], M2 = sm2[0];
    const int gi1 = si1[0];
    if (tid == 0) cnt = 0;
    __syncthreads();
    float e1 = 0.f, e2 = 0.f, p = 0.f;
    for (int j = tid; j < NROWS; j += STAT_THREADS) {
        const float x = row[j];
        const float sm = x - M1;
        e1 += __expf(sm);
        if (j != gi1) e2 += __expf(x - M2);
        if (labels[j & (B_SAMPLES - 1)] == c) {
            p += sm;
            if (j != gi1) { const int k = atomicAdd(&cnt, 1); if (k < FCAP) xs[k] = sm; }
        }
    }
    red4[tid] = make_float4(e1, e2, p, 0.f);
    __syncthreads();
    for (int s = STAT_THREADS / 2; s > 0; s >>= 1) {
        if (tid < s) {
            const float4 a = red4[tid], b4 = red4[tid + s];
            red4[tid] = make_float4(a.x + b4.x, a.y + b4.y, a.z + b4.z, 0.f);
        }
        __syncthreads();
    }
    const float E1 = red4[0].x, E2 = red4[0].y, P = red4[0].z;
    const int total = cnt;
    __syncthreads();
    float ls = 0.f;
    if (total <= FCAP) {
        for (int k = tid; k < total; k += STAT_THREADS) ls += __logf(E1 - __expf(xs[k]));
    } else {
        for (int j = tid; j < NROWS; j += STAT_THREADS)
            if (j != gi1 && labels[j & (B_SAMPLES - 1)] == c)
                ls += __logf(E1 - __expf(row[j] - M1));
    }
    red4[tid].x = ls;
    __syncthreads();
    for (int s = STAT_THREADS / 2; s > 0; s >>= 1) {
        if (tid < s) red4[tid].x += red4[tid + s].x;
        __syncthreads();
    }
    if (tid == 0) {
        float sumlog = red4[0].x;
        if (labels[gi1 & (B_SAMPLES - 1)] == c) sumlog += (M2 - M1) + __logf(E2);
        atomicAdd(out, (sumlog - P) / (float)NROWS);
    }
}

// ==========================================================================================
extern "C" void kernel_launch(void* const* d_in, const int* in_sizes, int n_in,
                              void* d_out, int out_size, void* d_ws, size_t ws_size,
                              hipStream_t stream) {
    const float* feats  = (const float*)d_in[0];
    const int*   labels = (const int*)d_in[1];
    const float* protos = (const float*)d_in[2];
    float* out = (float*)d_out;

    char* w = (char*)d_ws;
    size_t off = 0;
    auto take = [&](size_t n) { size_t o = off; off += (n + 255) & ~(size_t)255; return o; };
    float*          S    = (float*)(w + take((size_t)NCLS * NROWS * 4));
    unsigned short* cB   = (unsigned short*)(w + take((size_t)NROWS * DDIM * 2));
    unsigned short* pB   = (unsigned short*)(w + take((size_t)MPAD * DDIM * 2));
    float*          pM1  = (float*)(w + take(NCLS * JB * 4));
    float*          pM2  = (float*)(w + take(NCLS * JB * 4));
    int*            pI1  = (int*)(w + take(NCLS * JB * 4));
    float*          gE1  = (float*)(w + take(NCLS * 4));
    float*          gE2  = (float*)(w + take(NCLS * 4));
    float*          gP   = (float*)(w + take(NCLS * 4));
    int*            scnt = (int*)(w + take(NCLS * 4));
    float*          stash= (float*)(w + take(NCLS * STASH_CAP * 4));
    const size_t required = off;

    if (ws_size < required) {   // fallback: proven fp32 path (needs only S)
        float* Sf = (float*)d_ws;
        dim3 g1(NROWS / 256, NCLS / CPT);
        k_scores_fb<<<g1, 256, 0, stream>>>(feats, protos, Sf, out);
        k_stats_loss_fb<<<NCLS, STAT_THREADS, 0, stream>>>(Sf, labels, out);
        return;
    }

    k_convert<<<2077, 256, 0, stream>>>(feats, protos, cB, pB, gE1, gE2, gP, scnt, out);
    k_gemm<<<448, 256, 0, stream>>>(cB, pB, S);
    k_top2<<<dim3(JB, NCLS), 256, 0, stream>>>(S, pM1, pM2, pI1);
    k_expsum<<<dim3(JB, NCLS), 256, 0, stream>>>(S, labels, pM1, pM2, pI1, gE1, gE2, gP, stash, scnt);
    k_final<<<NCLS, 64, 0, stream>>>(S, labels, pM1, pM2, pI1, gE1, gE2, gP, stash, scnt, out);
}

// Round 4
// 109.409 us; speedup vs baseline: 1.5704x; 1.0213x over previous
//
#include <hip/hip_runtime.h>
#include <hip/hip_bf16.h>
#include <math.h>

#define BS 4096
#define DD 512
#define NCLS 100
#define NROWS 8192
#define INV_T (1.0f / 0.07f)
#define JB 8
#define CHUNK 1024
#define CAP 256              // stash capacity per class (E[matches]=82, sd~9)

typedef __attribute__((ext_vector_type(8))) short short8;      // 8 bf16 (4 VGPR)
typedef __attribute__((ext_vector_type(8))) unsigned short ushort8;
typedef __attribute__((ext_vector_type(4))) float f32x4;

__device__ __forceinline__ unsigned short f2bf(float x) {
    __hip_bfloat16 h = __float2bfloat16(x);
    return *reinterpret_cast<unsigned short*>(&h);
}

// ---- K1: protos fp32 -> bf16 (112 rows, zero-padded) ; zero counters & out ----
__global__ __launch_bounds__(256) void k_prep(const float* __restrict__ protos,
                                              unsigned short* __restrict__ pB,
                                              int* __restrict__ scnt, int* __restrict__ done,
                                              float* __restrict__ out) {
    const int bid = blockIdx.x, tid = threadIdx.x;
    if (bid < 28) {                         // 112*512/8 = 7168 8-elem chunks
        const int t = bid * 256 + tid;
        const int r = t >> 6;
        const int kk = (t & 63) << 3;
        float4 f0 = {0,0,0,0}, f1 = {0,0,0,0};
        if (r < NCLS) {
            const float4* s = (const float4*)(protos + (size_t)r * DD + kk);
            f0 = s[0]; f1 = s[1];
        }
        ushort8 o;
        o[0]=f2bf(f0.x); o[1]=f2bf(f0.y); o[2]=f2bf(f0.z); o[3]=f2bf(f0.w);
        o[4]=f2bf(f1.x); o[5]=f2bf(f1.y); o[6]=f2bf(f1.z); o[7]=f2bf(f1.w);
        *reinterpret_cast<ushort8*>(pB + (size_t)r * DD + kk) = o;
    } else {
        if (tid < NCLS) { scnt[tid] = 0; done[tid] = 0; }
        if (tid == 0) out[0] = 0.f;
    }
}

// ---- K2: S = protos @ contrast^T / T.  One block per 32-row contrast slab. ----
// Features converted fp32->bf16 exactly once, into XOR-swizzled LDS.
__global__ __launch_bounds__(448) void k_gemm(const float* __restrict__ feats,
                                              const unsigned short* __restrict__ pB,
                                              float* __restrict__ S) {
    __shared__ char lds[32 * DD * 2];        // 32 KB bf16 [32][512], byte ^= (row&7)<<4
    const int nt = blockIdx.x, tid = threadIdx.x;
    const int v  = nt >> 7;                  // view of this slab (rows 0..4095 -> v0)
    const int b0 = (nt & 127) * 32;          // first sample index

    for (int i = tid; i < 32 * DD / 4; i += 448) {   // 4096 float4 chunks
        const int r = i >> 7, c4 = i & 127;
        const float4 f = *(const float4*)(feats + (size_t)((b0 + r) * 2 + v) * DD + c4 * 4);
        ushort4 o = { f2bf(f.x), f2bf(f.y), f2bf(f.z), f2bf(f.w) };
        const int byte = (r * 1024 + c4 * 8) ^ ((r & 7) << 4);
        *reinterpret_cast<ushort4*>(&lds[byte]) = o;
    }
    __syncthreads();

    const int w = tid >> 6, lane = tid & 63; // 7 waves, wave w -> M-tile w
    const int m = lane & 15, kb = lane >> 4;
    const short* Ab = (const short*)pB + (size_t)(w * 16 + m) * DD + kb * 8;
    const int swz   = (m & 7) << 4;          // (m+16)&7 == m&7
    const int base0 = m * 1024 + kb * 16;
    const int base1 = (m + 16) * 1024 + kb * 16;
    f32x4 acc0 = {}, acc1 = {};
#pragma unroll
    for (int k = 0; k < 16; ++k) {           // K = 512 = 16 x 32
        const short8 a   = *reinterpret_cast<const short8*>(Ab + k * 32);
        const short8 bf0 = *reinterpret_cast<const short8*>(&lds[(base0 + k * 64) ^ swz]);
        const short8 bf1 = *reinterpret_cast<const short8*>(&lds[(base1 + k * 64) ^ swz]);
        acc0 = __builtin_amdgcn_mfma_f32_16x16x32_bf16(a, bf0, acc0, 0, 0, 0);
        acc1 = __builtin_amdgcn_mfma_f32_16x16x32_bf16(a, bf1, acc1, 0, 0, 0);
    }
    // C/D: col = lane&15, row = (lane>>4)*4 + r
    const int row0 = w * 16 + kb * 4;
    const int col  = nt * 32 + m;
#pragma unroll
    for (int r = 0; r < 4; ++r) {
        const int row = row0 + r;
        if (row < NCLS) {
            S[(size_t)row * NROWS + col]      = acc0[r] * INV_T;
            S[(size_t)row * NROWS + col + 16] = acc1[r] * INV_T;
        }
    }
}

// ---- K3: fused stats + loss.  Chunked LSE partials; last block per class merges. ----
__global__ __launch_bounds__(256) void k_stats(const float* __restrict__ S,
                                               const int* __restrict__ labels,
                                               float* pM1, float* pM2, int* pI1,
                                               float* pEa, float* pEe, float* pP, float* pN,
                                               float* stx, int* stj,
                                               int* scnt, int* done,
                                               float* __restrict__ out) {
    const int c = blockIdx.y, jb = blockIdx.x, tid = threadIdx.x;
    const int jbase = jb * CHUNK + tid * 4;
    const float4 xv = *(const float4*)(S + (size_t)c * NROWS + jbase);
    const int4   lv = *(const int4*)(labels + (jbase & (BS - 1)));
    const float x[4] = {xv.x, xv.y, xv.z, xv.w};
    const int  lb[4] = {lv.x, lv.y, lv.z, lv.w};

    __shared__ float s1[256], s2[256];
    __shared__ int   si[256];

    // local top-2 + argmax over this chunk
    float m1 = -INFINITY, m2 = -INFINITY; int i1 = -1;
#pragma unroll
    for (int e = 0; e < 4; ++e) {
        if (x[e] > m1)      { m2 = m1; m1 = x[e]; i1 = jbase + e; }
        else if (x[e] > m2) { m2 = x[e]; }
    }
    s1[tid] = m1; s2[tid] = m2; si[tid] = i1;
    __syncthreads();
    for (int s = 128; s > 0; s >>= 1) {
        if (tid < s) {
            const float b1 = s1[tid + s], b2 = s2[tid + s];
            if (b1 > s1[tid]) { s2[tid] = fmaxf(s1[tid], b2); s1[tid] = b1; si[tid] = si[tid + s]; }
            else              { s2[tid] = fmaxf(s2[tid], b1); }
        }
        __syncthreads();
    }
    const float M1 = s1[0], M2 = s2[0];
    const int   L1 = si[0];
    __syncthreads();

    // local-rescaled sums (values already in registers)
    float ea = 0.f, ee = 0.f, pp = 0.f, nn = 0.f;
#pragma unroll
    for (int e = 0; e < 4; ++e) {
        const int j = jbase + e;
        ea += __expf(x[e] - M1);
        if (j != L1) ee += __expf(x[e] - M2);
        if (lb[e] == c) {
            pp += x[e] - M1; nn += 1.f;
            const int k = atomicAdd(&scnt[c], 1);
            if (k < CAP) {
                atomicExch(&stx[c * CAP + k], x[e]);   // raw logit
                atomicExch(&stj[c * CAP + k], j);
            }
        }
    }
    __shared__ float4 r4[256];
    r4[tid] = make_float4(ea, ee, pp, nn);
    __syncthreads();
    for (int s = 128; s > 0; s >>= 1) {
        if (tid < s) {
            const float4 A = r4[tid], Bq = r4[tid + s];
            r4[tid] = make_float4(A.x + Bq.x, A.y + Bq.y, A.z + Bq.z, A.w + Bq.w);
        }
        __syncthreads();
    }

    __shared__ int sLast;
    if (tid == 0) {
        const int idx = c * JB + jb;
        const float4 R = r4[0];
        atomicExch(&pM1[idx], M1);
        atomicExch(&pM2[idx], M2);
        atomicExch(&pI1[idx], L1);
        atomicExch(&pEa[idx], R.x);
        atomicExch(&pEe[idx], R.y);
        atomicExch(&pP[idx],  R.z);
        atomicExch(&pN[idx],  R.w);
        __threadfence();
        sLast = (atomicAdd(&done[c], 1) == JB - 1);
    }
    __syncthreads();
    if (!sLast) return;

    // ---- merge phase (exactly one block per class) ----
    __shared__ float fM1[JB], fM2[JB], fEa[JB], fEe[JB], fP[JB], fN[JB];
    __shared__ int   fI1[JB];
    if (tid < JB) {                          // coherent RMW reads
        const int idx = c * JB + tid;
        fM1[tid] = atomicAdd(&pM1[idx], 0.f);
        fM2[tid] = atomicAdd(&pM2[idx], 0.f);
        fI1[tid] = atomicAdd(&pI1[idx], 0);
        fEa[tid] = atomicAdd(&pEa[idx], 0.f);
        fEe[tid] = atomicAdd(&pEe[idx], 0.f);
        fP[tid]  = atomicAdd(&pP[idx], 0.f);
        fN[tid]  = atomicAdd(&pN[idx], 0.f);
    }
    __shared__ float gv[5];
    __shared__ int   gi[2];
    if (tid == 64) gi[1] = atomicAdd(&scnt[c], 0);
    __syncthreads();
    if (tid == 0) {
        float gm1 = -INFINITY, gm2 = -INFINITY; int g1 = -1, win = -1;
        for (int l = 0; l < JB; ++l) {
            if (fM1[l] > gm1) { gm2 = fmaxf(gm1, fM2[l]); gm1 = fM1[l]; g1 = fI1[l]; win = l; }
            else              { gm2 = fmaxf(gm2, fM1[l]); }
        }
        float E1 = 0.f, E2 = 0.f, Pg = 0.f;
        for (int l = 0; l < JB; ++l) {
            E1 += fEa[l] * __expf(fM1[l] - gm1);           // exponents all <= 0
            Pg += fP[l] + fN[l] * (fM1[l] - gm1);
            E2 += (l == win) ? fEe[l] * __expf(fM2[l] - gm2)
                             : fEa[l] * __expf(fM1[l] - gm2);
        }
        gv[0] = gm1; gv[1] = gm2; gv[2] = E1; gv[3] = E2; gv[4] = Pg;
        gi[0] = g1;
    }
    __syncthreads();
    const float gm1 = gv[0], gm2 = gv[1], E1 = gv[2], E2 = gv[3], Pg = gv[4];
    const int   gi1 = gi[0], total = gi[1];

    float ls = 0.f;
    if (total <= CAP) {
        for (int k = tid; k < total; k += 256) {
            const float xk = atomicAdd(&stx[c * CAP + k], 0.f);
            const int   jk = atomicAdd(&stj[c * CAP + k], 0);
            ls += (jk == gi1) ? (gm2 - gm1) + __logf(E2)          // cancellation-free argmax row
                              : __logf(E1 - __expf(xk - gm1));    // >= 1 always
        }
    } else {                                  // pathological fallback: rescan row
        for (int j = tid; j < NROWS; j += 256) {
            if (labels[j & (BS - 1)] == c) {
                const float xj = S[(size_t)c * NROWS + j];
                ls += (j == gi1) ? (gm2 - gm1) + __logf(E2)
                                 : __logf(E1 - __expf(xj - gm1));
            }
        }
    }
    s1[tid] = ls;
    __syncthreads();
    for (int s = 128; s > 0; s >>= 1) {
        if (tid < s) s1[tid] += s1[tid + s];
        __syncthreads();
    }
    if (tid == 0) atomicAdd(out, (s1[0] - Pg) / (float)NROWS);
}

// ==========================================================================
extern "C" void kernel_launch(void* const* d_in, const int* in_sizes, int n_in,
                              void* d_out, int out_size, void* d_ws, size_t ws_size,
                              hipStream_t stream) {
    const float* feats  = (const float*)d_in[0];
    const int*   labels = (const int*)d_in[1];
    const float* protos = (const float*)d_in[2];
    float* out = (float*)d_out;

    char* w = (char*)d_ws;
    size_t off = 0;
    auto take = [&](size_t n) { size_t o = off; off += (n + 255) & ~(size_t)255; return o; };
    float*          S    = (float*)(w + take((size_t)NCLS * NROWS * 4));
    unsigned short* pB   = (unsigned short*)(w + take((size_t)112 * DD * 2));
    float*          pM1  = (float*)(w + take(NCLS * JB * 4));
    float*          pM2  = (float*)(w + take(NCLS * JB * 4));
    int*            pI1  = (int*)(w + take(NCLS * JB * 4));
    float*          pEa  = (float*)(w + take(NCLS * JB * 4));
    float*          pEe  = (float*)(w + take(NCLS * JB * 4));
    float*          pP   = (float*)(w + take(NCLS * JB * 4));
    float*          pN   = (float*)(w + take(NCLS * JB * 4));
    float*          stx  = (float*)(w + take(NCLS * CAP * 4));
    int*            stj  = (int*)(w + take(NCLS * CAP * 4));
    int*            scnt = (int*)(w + take(NCLS * 4));
    int*            done = (int*)(w + take(NCLS * 4));

    k_prep<<<29, 256, 0, stream>>>(protos, pB, scnt, done, out);
    k_gemm<<<256, 448, 0, stream>>>(feats, pB, S);
    k_stats<<<dim3(JB, NCLS), 256, 0, stream>>>(S, labels, pM1, pM2, pI1,
                                                pEa, pEe, pP, pN, stx, stj,
                                                scnt, done, out);
}

// Round 6
// 89.873 us; speedup vs baseline: 1.9118x; 1.2174x over previous
//
#include <hip/hip_runtime.h>
#include <hip/hip_bf16.h>
#include <math.h>

#define BS 4096
#define DD 512
#define NCLS 100
#define NROWS 8192
#define NSLAB 256            // 256 slabs x 32 cols
#define INV_T (1.0f / 0.07f)

typedef __attribute__((ext_vector_type(8))) short short8;      // 8 bf16 (4 VGPR)
typedef __attribute__((ext_vector_type(4))) float f32x4;

__device__ __forceinline__ unsigned short f2bf(float x) {
    __hip_bfloat16 h = __float2bfloat16(x);
    return *reinterpret_cast<unsigned short*>(&h);
}

// ---- K1: GEMM (112x32 logits per block, in regs) + per-(class,slab) stats + stash ----
// Block nt owns contrast columns [nt*32, nt*32+32). 7 waves x 16 M-rows.
__global__ __launch_bounds__(448) void k_gemm(const float* __restrict__ feats,
                                              const float* __restrict__ protos,
                                              const int* __restrict__ labels,
                                              float4* __restrict__ PA,   // [NCLS][NSLAB] {m1,m2,ea,ee}
                                              float4* __restrict__ PB,   // [NCLS][NSLAB] {pp,nn,i1,0}
                                              float* __restrict__ stash, // [NROWS] matched logit per col
                                              float* __restrict__ out) {
    __shared__ char lds[32 * DD * 2];        // 32 KB bf16 [32][512], byte ^= (row&7)<<4
    const int nt = blockIdx.x, tid = threadIdx.x;
    if (nt == 0 && tid == 0) out[0] = 0.f;   // k_merge runs after this kernel completes
    const int v  = nt >> 7;
    const int b0 = (nt & 127) * 32;

    // stage feature slab -> swizzled bf16 LDS (each feature read exactly once globally)
    for (int i = tid; i < 32 * DD / 4; i += 448) {
        const int r = i >> 7, c4 = i & 127;
        const float4 f = *(const float4*)(feats + (size_t)((b0 + r) * 2 + v) * DD + c4 * 4);
        ushort4 o = { f2bf(f.x), f2bf(f.y), f2bf(f.z), f2bf(f.w) };
        const int byte = (r * 1024 + c4 * 8) ^ ((r & 7) << 4);
        *reinterpret_cast<ushort4*>(&lds[byte]) = o;
    }

    const int w = tid >> 6, lane = tid & 63;
    const int m = lane & 15, kb = lane >> 4;

    // A-fragments: fp32 protos -> bf16 registers (row clamped; rows >=100 discarded later)
    const int arow = min(w * 16 + m, NCLS - 1);
    const float* ap = protos + (size_t)arow * DD + kb * 8;
    short8 areg[16];
#pragma unroll
    for (int k = 0; k < 16; ++k) {
        const float4 lo = *(const float4*)(ap + k * 32);
        const float4 hi = *(const float4*)(ap + k * 32 + 4);
        short8 a;
        a[0]=f2bf(lo.x); a[1]=f2bf(lo.y); a[2]=f2bf(lo.z); a[3]=f2bf(lo.w);
        a[4]=f2bf(hi.x); a[5]=f2bf(hi.y); a[6]=f2bf(hi.z); a[7]=f2bf(hi.w);
        areg[k] = a;
    }
    __syncthreads();

    const int swz   = (m & 7) << 4;          // (m+16)&7 == m&7
    const int base0 = m * 1024 + kb * 16;
    const int base1 = (m + 16) * 1024 + kb * 16;
    f32x4 acc0 = {}, acc1 = {};
#pragma unroll
    for (int k = 0; k < 16; ++k) {
        const short8 bf0 = *reinterpret_cast<const short8*>(&lds[(base0 + k * 64) ^ swz]);
        const short8 bf1 = *reinterpret_cast<const short8*>(&lds[(base1 + k * 64) ^ swz]);
        acc0 = __builtin_amdgcn_mfma_f32_16x16x32_bf16(areg[k], bf0, acc0, 0, 0, 0);
        acc1 = __builtin_amdgcn_mfma_f32_16x16x32_bf16(areg[k], bf1, acc1, 0, 0, 0);
    }
#pragma unroll
    for (int r = 0; r < 4; ++r) { acc0[r] *= INV_T; acc1[r] *= INV_T; }

    // C/D layout: col = lane&15 (+16 for acc1), row = w*16 + kb*4 + r
    const int j0 = nt * 32 + m, j1 = j0 + 16;
    const int lb0 = labels[j0 & (BS - 1)], lb1 = labels[j1 & (BS - 1)];

    // stash: column j's matched logit is S[label[j]][j] — exactly one lane holds it
    if ((lb0 >> 4) == w && ((lb0 >> 2) & 3) == kb) {
        const int rr = lb0 & 3;
        stash[j0] = (rr==0)?acc0[0]:(rr==1)?acc0[1]:(rr==2)?acc0[2]:acc0[3];
    }
    if ((lb1 >> 4) == w && ((lb1 >> 2) & 3) == kb) {
        const int rr = lb1 & 3;
        stash[j1] = (rr==0)?acc1[0]:(rr==1)?acc1[1]:(rr==2)?acc1[2]:acc1[3];
    }

    // per-class-row stats over this slab's 32 columns: 16-lane shfl butterflies
#pragma unroll
    for (int r = 0; r < 4; ++r) {
        const int row = w * 16 + kb * 4 + r;
        const float x0 = acc0[r], x1 = acc1[r];
        float m1, m2; int i1;
        if (x0 >= x1) { m1 = x0; m2 = x1; i1 = j0; } else { m1 = x1; m2 = x0; i1 = j1; }
#pragma unroll
        for (int s = 1; s < 16; s <<= 1) {   // disjoint-union butterfly: exact top-2
            const float om1 = __shfl_xor(m1, s);
            const float om2 = __shfl_xor(m2, s);
            const int   oi1 = __shfl_xor(i1, s);
            if (om1 > m1) { m2 = fmaxf(m1, om2); m1 = om1; i1 = oi1; }
            else          { m2 = fmaxf(m2, om1); }
        }
        float ea = __expf(x0 - m1) + __expf(x1 - m1);
        float ee = (j0 != i1 ? __expf(x0 - m2) : 0.f) + (j1 != i1 ? __expf(x1 - m2) : 0.f);
        float pp = 0.f, nn = 0.f;
        if (lb0 == row) { pp += x0 - m1; nn += 1.f; }
        if (lb1 == row) { pp += x1 - m1; nn += 1.f; }
#pragma unroll
        for (int s = 1; s < 16; s <<= 1) {
            ea += __shfl_xor(ea, s);
            ee += __shfl_xor(ee, s);
            pp += __shfl_xor(pp, s);
            nn += __shfl_xor(nn, s);
        }
        if (m == 0 && row < NCLS) {          // plain stores; next kernel sees them
            PA[row * NSLAB + nt] = make_float4(m1, m2, ea, ee);
            PB[row * NSLAB + nt] = make_float4(pp, nn, (float)i1, 0.f);
        }
    }
}

// ---- K2: per-class merge of 256 slab partials + loss ----
__global__ __launch_bounds__(256) void k_merge(const float4* __restrict__ PA,
                                               const float4* __restrict__ PB,
                                               const float* __restrict__ stash,
                                               const int* __restrict__ labels,
                                               float* __restrict__ out) {
    const int c = blockIdx.x, tid = threadIdx.x;
    const float4 A  = PA[c * NSLAB + tid];
    const float4 Bq = PB[c * NSLAB + tid];
    const float m1 = A.x, m2 = A.y, ea = A.z, ee = A.w;
    const float pp = Bq.x, nn = Bq.y;
    const int   i1 = (int)Bq.z;

    __shared__ float s1[256], s2[256];
    __shared__ int   si[256];
    s1[tid] = m1; s2[tid] = m2; si[tid] = i1;
    __syncthreads();
    for (int s = 128; s > 0; s >>= 1) {
        if (tid < s) {
            const float b1 = s1[tid + s], b2 = s2[tid + s];
            if (b1 > s1[tid]) { s2[tid] = fmaxf(s1[tid], b2); s1[tid] = b1; si[tid] = si[tid + s]; }
            else              { s2[tid] = fmaxf(s2[tid], b1); }
        }
        __syncthreads();
    }
    const float gm1 = s1[0], gm2 = s2[0];
    const int   gi1 = si[0];
    __syncthreads();

    // rescaled contributions (all exponents <= 0)
    const float e1c = ea * __expf(m1 - gm1);
    const float e2c = ((gi1 >> 5) == tid) ? ee * __expf(m2 - gm2)
                                          : ea * __expf(m1 - gm2);
    const float pc  = pp + nn * (m1 - gm1);
    __shared__ float r1[256], r2[256], r3[256];
    r1[tid] = e1c; r2[tid] = e2c; r3[tid] = pc;
    __syncthreads();
    for (int s = 128; s > 0; s >>= 1) {
        if (tid < s) { r1[tid] += r1[tid + s]; r2[tid] += r2[tid + s]; r3[tid] += r3[tid + s]; }
        __syncthreads();
    }
    const float E1 = r1[0], E2 = r2[0], Pg = r3[0];
    __syncthreads();

    // loss over matched columns (label[j]==c); stash[j] = S[c][j]
    float ls = 0.f;
    for (int j = tid; j < NROWS; j += 256) {
        if (labels[j & (BS - 1)] == c) {
            const float xj = stash[j];
            ls += (j == gi1) ? (gm2 - gm1) + __logf(E2)          // cancellation-free argmax row
                             : __logf(E1 - __expf(xj - gm1));    // >= 1 always (argmax term remains)
        }
    }
    s1[tid] = ls;
    __syncthreads();
    for (int s = 128; s > 0; s >>= 1) {
        if (tid < s) s1[tid] += s1[tid + s];
        __syncthreads();
    }
    if (tid == 0) atomicAdd(out, (s1[0] - Pg) / (float)NROWS);
}

// ==========================================================================
extern "C" void kernel_launch(void* const* d_in, const int* in_sizes, int n_in,
                              void* d_out, int out_size, void* d_ws, size_t ws_size,
                              hipStream_t stream) {
    const float* feats  = (const float*)d_in[0];
    const int*   labels = (const int*)d_in[1];
    const float* protos = (const float*)d_in[2];
    float* out = (float*)d_out;

    char* w = (char*)d_ws;
    size_t off = 0;
    auto take = [&](size_t n) { size_t o = off; off += (n + 255) & ~(size_t)255; return o; };
    float4* PA    = (float4*)(w + take((size_t)NCLS * NSLAB * 16));
    float4* PB    = (float4*)(w + take((size_t)NCLS * NSLAB * 16));
    float*  stash = (float*)(w + take((size_t)NROWS * 4));

    k_gemm<<<NSLAB, 448, 0, stream>>>(feats, protos, labels, PA, PB, stash, out);
    k_merge<<<NCLS, 256, 0, stream>>>(PA, PB, stash, labels, out);
}

// Round 7
// 83.801 us; speedup vs baseline: 2.0503x; 1.0725x over previous
//
#include <hip/hip_runtime.h>
#include <hip/hip_bf16.h>
#include <math.h>

#define BS 4096
#define DD 512
#define NCLS 100
#define NROWS 8192
#define NSLAB 256            // 256 slabs x 32 cols
#define INV_T (1.0f / 0.07f)

typedef __attribute__((ext_vector_type(8))) short short8;      // 8 bf16 (4 VGPR)
typedef __attribute__((ext_vector_type(4))) float f32x4;

__device__ __forceinline__ unsigned short f2bf(float x) {
    __hip_bfloat16 h = __float2bfloat16(x);
    return *reinterpret_cast<unsigned short*>(&h);
}

// ---- K1: GEMM (128x32 logits per block, in regs) + per-(class,slab) stats + stash ----
// Block nt owns contrast columns [nt*32, nt*32+32). 8 waves; wave w -> M-rows [w*16, w*16+16)
// (rows 100..127 are clamped duplicates of row 99, never published).
__global__ __launch_bounds__(512) void k_gemm(const float* __restrict__ feats,
                                              const float* __restrict__ protos,
                                              const int* __restrict__ labels,
                                              float4* __restrict__ PA,   // [NCLS][NSLAB] {m1,m2,ea,ee}
                                              float4* __restrict__ PB,   // [NCLS][NSLAB] {pp,nn,i1,0}
                                              float* __restrict__ stash, // [NROWS] matched logit per col
                                              float* __restrict__ out) {
    __shared__ char lds[32 * DD * 2];        // 32 KB bf16 [32][512], byte ^= (row&7)<<4
    const int nt = blockIdx.x, tid = threadIdx.x;
    if (nt == 0 && tid == 0) out[0] = 0.f;   // k_merge runs after this kernel completes
    const int v  = nt >> 7;
    const int b0 = (nt & 127) * 32;

    // (a) issue ALL 8 feature loads -> registers (one HBM latency, not 8)
    float4 fr[8];
#pragma unroll
    for (int it = 0; it < 8; ++it) {
        const int i = tid + it * 512;        // 4096 float4 chunks, coalesced
        const int r = i >> 7, c4 = i & 127;
        fr[it] = *(const float4*)(feats + (size_t)((b0 + r) * 2 + v) * DD + c4 * 4);
    }
    // (b) convert + swizzled LDS write
#pragma unroll
    for (int it = 0; it < 8; ++it) {
        const int i = tid + it * 512;
        const int r = i >> 7, c4 = i & 127;
        ushort4 o = { f2bf(fr[it].x), f2bf(fr[it].y), f2bf(fr[it].z), f2bf(fr[it].w) };
        const int byte = (r * 1024 + c4 * 8) ^ ((r & 7) << 4);
        *reinterpret_cast<ushort4*>(&lds[byte]) = o;
    }
    __syncthreads();

    const int w = tid >> 6, lane = tid & 63;
    const int m = lane & 15, kb = lane >> 4;
    const int arow = min(w * 16 + m, NCLS - 1);            // clamp: rows >=100 discarded later
    const float4* ap = (const float4*)(protos + (size_t)arow * DD + kb * 8);

    const int swz   = (m & 7) << 4;          // (m+16)&7 == m&7
    const int base0 = m * 1024 + kb * 16;
    const int base1 = (m + 16) * 1024 + kb * 16;
    f32x4 acc0 = {}, acc1 = {};
#pragma unroll
    for (int k = 0; k < 16; ++k) {           // K = 512 = 16 x 32 ; A streamed (no areg[16])
        const float4 lo = ap[k * 8];         // L2-warm after first blocks; pipelined ahead
        const float4 hi = ap[k * 8 + 1];
        short8 a;
        a[0]=f2bf(lo.x); a[1]=f2bf(lo.y); a[2]=f2bf(lo.z); a[3]=f2bf(lo.w);
        a[4]=f2bf(hi.x); a[5]=f2bf(hi.y); a[6]=f2bf(hi.z); a[7]=f2bf(hi.w);
        const short8 bf0 = *reinterpret_cast<const short8*>(&lds[(base0 + k * 64) ^ swz]);
        const short8 bf1 = *reinterpret_cast<const short8*>(&lds[(base1 + k * 64) ^ swz]);
        acc0 = __builtin_amdgcn_mfma_f32_16x16x32_bf16(a, bf0, acc0, 0, 0, 0);
        acc1 = __builtin_amdgcn_mfma_f32_16x16x32_bf16(a, bf1, acc1, 0, 0, 0);
    }
#pragma unroll
    for (int r = 0; r < 4; ++r) { acc0[r] *= INV_T; acc1[r] *= INV_T; }

    // C/D layout: col = lane&15 (+16 for acc1), row = w*16 + kb*4 + r
    const int j0 = nt * 32 + m, j1 = j0 + 16;
    const int lb0 = labels[j0 & (BS - 1)], lb1 = labels[j1 & (BS - 1)];

    // stash: column j's matched logit is S[label[j]][j] — exactly one lane holds it (lb<100 -> w<=6)
    if ((lb0 >> 4) == w && ((lb0 >> 2) & 3) == kb) {
        const int rr = lb0 & 3;
        stash[j0] = (rr==0)?acc0[0]:(rr==1)?acc0[1]:(rr==2)?acc0[2]:acc0[3];
    }
    if ((lb1 >> 4) == w && ((lb1 >> 2) & 3) == kb) {
        const int rr = lb1 & 3;
        stash[j1] = (rr==0)?acc1[0]:(rr==1)?acc1[1]:(rr==2)?acc1[2]:acc1[3];
    }

    // per-class-row stats over this slab's 32 columns: 16-lane shfl butterflies
    // (the 4 r-chains are independent -> compiler interleaves their latencies)
#pragma unroll
    for (int r = 0; r < 4; ++r) {
        const int row = w * 16 + kb * 4 + r;
        const float x0 = acc0[r], x1 = acc1[r];
        float m1, m2; int i1;
        if (x0 >= x1) { m1 = x0; m2 = x1; i1 = j0; } else { m1 = x1; m2 = x0; i1 = j1; }
#pragma unroll
        for (int s = 1; s < 16; s <<= 1) {   // disjoint-union butterfly: exact top-2
            const float om1 = __shfl_xor(m1, s);
            const float om2 = __shfl_xor(m2, s);
            const int   oi1 = __shfl_xor(i1, s);
            if (om1 > m1) { m2 = fmaxf(m1, om2); m1 = om1; i1 = oi1; }
            else          { m2 = fmaxf(m2, om1); }
        }
        float ea = __expf(x0 - m1) + __expf(x1 - m1);
        float ee = (j0 != i1 ? __expf(x0 - m2) : 0.f) + (j1 != i1 ? __expf(x1 - m2) : 0.f);
        float pp = 0.f, nn = 0.f;
        if (lb0 == row) { pp += x0 - m1; nn += 1.f; }
        if (lb1 == row) { pp += x1 - m1; nn += 1.f; }
#pragma unroll
        for (int s = 1; s < 16; s <<= 1) {
            ea += __shfl_xor(ea, s);
            ee += __shfl_xor(ee, s);
            pp += __shfl_xor(pp, s);
            nn += __shfl_xor(nn, s);
        }
        if (m == 0 && row < NCLS) {          // plain stores; next kernel sees them
            PA[row * NSLAB + nt] = make_float4(m1, m2, ea, ee);
            PB[row * NSLAB + nt] = make_float4(pp, nn, (float)i1, 0.f);
        }
    }
}

// ---- K2: per-class merge of 256 slab partials + loss ----
__global__ __launch_bounds__(256) void k_merge(const float4* __restrict__ PA,
                                               const float4* __restrict__ PB,
                                               const float* __restrict__ stash,
                                               const int* __restrict__ labels,
                                               float* __restrict__ out) {
    const int c = blockIdx.x, tid = threadIdx.x;
    const float4 A  = PA[c * NSLAB + tid];
    const float4 Bq = PB[c * NSLAB + tid];
    const float m1 = A.x, m2 = A.y, ea = A.z, ee = A.w;
    const float pp = Bq.x, nn = Bq.y;
    const int   i1 = (int)Bq.z;

    __shared__ float s1[256], s2[256];
    __shared__ int   si[256];
    s1[tid] = m1; s2[tid] = m2; si[tid] = i1;
    __syncthreads();
    for (int s = 128; s > 0; s >>= 1) {
        if (tid < s) {
            const float b1 = s1[tid + s], b2 = s2[tid + s];
            if (b1 > s1[tid]) { s2[tid] = fmaxf(s1[tid], b2); s1[tid] = b1; si[tid] = si[tid + s]; }
            else              { s2[tid] = fmaxf(s2[tid], b1); }
        }
        __syncthreads();
    }
    const float gm1 = s1[0], gm2 = s2[0];
    const int   gi1 = si[0];
    __syncthreads();

    // rescaled contributions (all exponents <= 0)
    const float e1c = ea * __expf(m1 - gm1);
    const float e2c = ((gi1 >> 5) == tid) ? ee * __expf(m2 - gm2)
                                          : ea * __expf(m1 - gm2);
    const float pc  = pp + nn * (m1 - gm1);
    __shared__ float r1[256], r2[256], r3[256];
    r1[tid] = e1c; r2[tid] = e2c; r3[tid] = pc;
    __syncthreads();
    for (int s = 128; s > 0; s >>= 1) {
        if (tid < s) { r1[tid] += r1[tid + s]; r2[tid] += r2[tid + s]; r3[tid] += r3[tid + s]; }
        __syncthreads();
    }
    const float E1 = r1[0], E2 = r2[0], Pg = r3[0];
    __syncthreads();

    // loss over matched columns (label[j]==c); stash[j] = S[c][j]
    float ls = 0.f;
    const float tmax = (gm2 - gm1) + __logf(E2);             // cancellation-free argmax row
    for (int it = 0; it < 8; ++it) {
        const int j = it * 1024 + tid * 4;
        const int4   lv = *(const int4*)(labels + (j & (BS - 1)));
        const float4 sv = *(const float4*)(stash + j);
        if (lv.x == c) ls += (j + 0 == gi1) ? tmax : __logf(E1 - __expf(sv.x - gm1));
        if (lv.y == c) ls += (j + 1 == gi1) ? tmax : __logf(E1 - __expf(sv.y - gm1));
        if (lv.z == c) ls += (j + 2 == gi1) ? tmax : __logf(E1 - __expf(sv.z - gm1));
        if (lv.w == c) ls += (j + 3 == gi1) ? tmax : __logf(E1 - __expf(sv.w - gm1));
    }
    s1[tid] = ls;
    __syncthreads();
    for (int s = 128; s > 0; s >>= 1) {
        if (tid < s) s1[tid] += s1[tid + s];
        __syncthreads();
    }
    if (tid == 0) atomicAdd(out, (s1[0] - Pg) / (float)NROWS);
}

// ==========================================================================
extern "C" void kernel_launch(void* const* d_in, const int* in_sizes, int n_in,
                              void* d_out, int out_size, void* d_ws, size_t ws_size,
                              hipStream_t stream) {
    const float* feats  = (const float*)d_in[0];
    const int*   labels = (const int*)d_in[1];
    const float* protos = (const float*)d_in[2];
    float* out = (float*)d_out;

    char* w = (char*)d_ws;
    size_t off = 0;
    auto take = [&](size_t n) { size_t o = off; off += (n + 255) & ~(size_t)255; return o; };
    float4* PA    = (float4*)(w + take((size_t)NCLS * NSLAB * 16));
    float4* PB    = (float4*)(w + take((size_t)NCLS * NSLAB * 16));
    float*  stash = (float*)(w + take((size_t)NROWS * 4));

    k_gemm<<<NSLAB, 512, 0, stream>>>(feats, protos, labels, PA, PB, stash, out);
    k_merge<<<NCLS, 256, 0, stream>>>(PA, PB, stash, labels, out);
}